// Round 12
// baseline (109.958 us; speedup 1.0000x reference)
//
#include <hip/hip_runtime.h>
#include <cstddef>

#define B_ 256
#define H_ 512
#define KF 256
#define BH 131072    // B_*H_
#define BH4 32768    // BH/4
#define H4 128       // H_/4

#define BM 64
#define BN 64
#define BK 16

__device__ __forceinline__ float sigmoidf_(float x) { return 1.0f / (1.0f + __expf(-x)); }
__device__ __forceinline__ float tanh_fast(float x) { return 2.0f / (1.0f + __expf(-2.0f * x)) - 1.0f; }
__device__ __forceinline__ float4 sig4(float4 v) {
    return make_float4(sigmoidf_(v.x), sigmoidf_(v.y), sigmoidf_(v.z), sigmoidf_(v.w));
}

#define MAC_LOOP()                                                         \
    _Pragma("unroll")                                                      \
    for (int kk = 0; kk < BK; ++kk) {                                      \
        const float4 a = *(const float4*)&As[kk][ty << 2];                 \
        const float4 w = *(const float4*)&Ws[kk][tx << 2];                 \
        const float a4[4] = {a.x, a.y, a.z, a.w};                          \
        const float w4[4] = {w.x, w.y, w.z, w.w};                          \
        _Pragma("unroll")                                                  \
        for (int i = 0; i < 4; ++i)                                        \
            _Pragma("unroll")                                              \
            for (int j = 0; j < 4; ++j)                                    \
                acc[i][j] = fmaf(a4[i], w4[j], acc[i][j]);                 \
    }

// ---------------------------------------------------------------------------
// 64x64-tile split-K partial GEMM over a K-chunk, register double-stage.
// ---------------------------------------------------------------------------
template<bool MUL>
__device__ __forceinline__ void gemm64(
    float (*As)[BM + 4], float (*Ws)[BN + 4],
    const float* __restrict__ abase, const float* __restrict__ rbase,
    const float* __restrict__ W, int Ktot, int ks,
    int bm, int bn, int nIter, float* __restrict__ p)
{
    const int tid = threadIdx.x;
    const int ty = tid >> 4, tx = tid & 15;
    const int lrow = tid >> 2, lcol = (tid & 3) << 2;
    const float* aptr = abase + (bm + lrow) * 512 + lcol;
    const float* rptr = MUL ? rbase + (bm + lrow) * 512 + lcol : nullptr;
    const float* wptr = W + (size_t)(bn + lrow) * Ktot + ks + lcol;

    float acc[4][4] = {};
    float4 av = *(const float4*)aptr;
    if (MUL) { const float4 rv = *(const float4*)rptr;
               av.x *= rv.x; av.y *= rv.y; av.z *= rv.z; av.w *= rv.w; }
    float4 wv = *(const float4*)wptr;

    for (int it = 0; it < nIter; ++it) {
        __syncthreads();
        As[lcol + 0][lrow] = av.x; As[lcol + 1][lrow] = av.y;
        As[lcol + 2][lrow] = av.z; As[lcol + 3][lrow] = av.w;
        Ws[lcol + 0][lrow] = wv.x; Ws[lcol + 1][lrow] = wv.y;
        Ws[lcol + 2][lrow] = wv.z; Ws[lcol + 3][lrow] = wv.w;
        __syncthreads();
        if (it < nIter - 1) {
            av = *(const float4*)(aptr + (it + 1) * BK);
            if (MUL) { const float4 rv = *(const float4*)(rptr + (it + 1) * BK);
                       av.x *= rv.x; av.y *= rv.y; av.z *= rv.z; av.w *= rv.w; }
            wv = *(const float4*)(wptr + (it + 1) * BK);
        }
        MAC_LOOP();
    }
    #pragma unroll
    for (int i = 0; i < 4; ++i) {
        const int m = bm + (ty << 2) + i;
        #pragma unroll
        for (int j = 0; j < 4; ++j)
            p[m * 512 + bn + (tx << 2) + j] = acc[i][j];
    }
}

// All input-only GEMM parts in one launch. z 0..5: d splits (K=1536) ->
// dbase slices 0..5 (hc1 dead space); z 6..13: r (0..3) / z (4..7) -> rzbase.
__global__ __launch_bounds__(256) void k_gemm_drz(
    const float* __restrict__ sample, const float* __restrict__ hidden,
    const float* __restrict__ d0,
    const float* __restrict__ Wd, const float* __restrict__ Wr,
    const float* __restrict__ Wz,
    float* __restrict__ dbase, float* __restrict__ rzbase)
{
    __shared__ float As[BK][BM + 4];
    __shared__ float Ws[BK][BN + 4];
    const int z = blockIdx.z;
    if (z < 6) {
        const int ks = z << 8, seg = ks >> 9;
        const float* ab = (seg == 0 ? sample : (seg == 1 ? hidden : d0)) + (ks & 511);
        gemm64<false>(As, Ws, ab, nullptr, Wd, 1536, ks,
                      blockIdx.y * BM, blockIdx.x * BN, 16, dbase + (size_t)z * BH);
    } else {
        const int id = z - 6, gz = id >> 2, s = id & 3, ks = s << 8;
        const float* ab = (ks < 512 ? sample + ks : hidden + (ks - 512));
        gemm64<false>(As, Ws, ab, nullptr, gz ? Wz : Wr, 1024, ks,
                      blockIdx.y * BM, blockIdx.x * BN, 16, rzbase + (size_t)id * BH);
    }
}

// dv/rb/zb reduce: consumes d-parts (hc1 slices 0..5, dead afterwards) and
// r/z parts (ws 0..7, dead afterwards -> reused for h-parts and accs).
__global__ __launch_bounds__(256) void k_dv(
    const float4* __restrict__ dparts, const float4* __restrict__ bd,
    const float4* __restrict__ rzparts, const float4* __restrict__ br,
    const float4* __restrict__ bz,
    float4* __restrict__ dv4, float4* __restrict__ rb4, float4* __restrict__ zb4)
{
    const int g = blockIdx.x * 256 + threadIdx.x;
    const int n = g & (H4 - 1);
    float4 sd = bd[n], sr = br[n], sz = bz[n];
    #pragma unroll
    for (int s = 0; s < 6; ++s) { const float4 p = dparts[(size_t)s * BH4 + g];
        sd.x += p.x; sd.y += p.y; sd.z += p.z; sd.w += p.w; }
    #pragma unroll
    for (int s = 0; s < 4; ++s) { const float4 p = rzparts[(size_t)s * BH4 + g];
        sr.x += p.x; sr.y += p.y; sr.z += p.z; sr.w += p.w; }
    #pragma unroll
    for (int s = 4; s < 8; ++s) { const float4 p = rzparts[(size_t)s * BH4 + g];
        sz.x += p.x; sz.y += p.y; sz.z += p.z; sz.w += p.w; }
    const float4 d = sig4(sd);
    dv4[g] = make_float4(0.5f * d.x, 0.5f * d.y, 0.5f * d.z, 0.5f * d.w);
    rb4[g] = sig4(sr);
    zb4[g] = sig4(sz);
}

// ---------------------------------------------------------------------------
// mega_A (READ-ONLY phase): bid<128 = h-GEMM -> ws slices 0..3;
// bid 128..1151 = filter, 8 contiguous descending K-segments x 128 blocks,
// batch-8 float4 loads, local cumprod from 1; acc_s -> ws slice
// (s<4 ? 4+s : 6+s). NO hc1 stores (copy phase is separate).
// ---------------------------------------------------------------------------
#define FLOADB(buf, b)                                                     \
    _Pragma("unroll")                                                      \
    for (int u = 0; u < 8; ++u)                                            \
        buf[u] = ld_base[-(ptrdiff_t)((b) * 8 + u) * BH4];

#define FCACC(buf, b)                                                      \
    _Pragma("unroll")                                                      \
    for (int u = 0; u < 8; ++u) {                                          \
        const int t = t0 + (b) * 8 + u;                                    \
        const float iv = s_inv[t], tv = s_tinv[t];                         \
        c.x *= fmaf(-d.x, iv, tv); c.y *= fmaf(-d.y, iv, tv);              \
        c.z *= fmaf(-d.z, iv, tv); c.w *= fmaf(-d.w, iv, tv);              \
        a.x = fmaf(buf[u].x, c.x, a.x); a.y = fmaf(buf[u].y, c.y, a.y);    \
        a.z = fmaf(buf[u].z, c.z, a.z); a.w = fmaf(buf[u].w, c.w, a.w);    \
    }

__global__ __launch_bounds__(256, 4) void k_mega_A(
    const float4* __restrict__ ht4, const float4* __restrict__ dv4,
    const float* __restrict__ sample, const float* __restrict__ hidden,
    const float* __restrict__ rb, const float* __restrict__ Wh,
    float* __restrict__ ws)
{
    const int bid = blockIdx.x;
    const int tid = threadIdx.x;
    if (bid < 128) {
        __shared__ float As[BK][BM + 4];
        __shared__ float Wsh[BK][BN + 4];
        const int s = bid >> 5, t2 = bid & 31;
        const int bn = (t2 >> 2) << 6, bm = (t2 & 3) << 6, ks = s << 8;
        if (ks < 512)
            gemm64<false>(As, Wsh, sample + ks, nullptr, Wh, 1024, ks, bm, bn, 16,
                          ws + (size_t)s * BH);
        else
            gemm64<true>(As, Wsh, hidden + (ks - 512), rb + (ks - 512), Wh, 1024, ks,
                         bm, bn, 16, ws + (size_t)s * BH);
        return;
    }

    __shared__ float s_inv[KF], s_tinv[KF];
    {
        const float fi = 1.0f / (float)(tid + 1);
        s_inv[tid] = fi; s_tinv[tid] = (float)tid * fi;
    }
    __syncthreads();

    const int fidx = bid - 128;                      // 0..1023
    const int seg = fidx >> 7;                       // 0..7
    const int q   = ((fidx & 127) << 8) | tid;       // float4-column 0..32767
    const float4 d = dv4[q];
    const int t0 = seg << 5;                         // 32 t-steps per segment

    const float4* ld_base = ht4 + (size_t)(255 - t0) * BH4 + q;

    float4 c = make_float4(1.f, 1.f, 1.f, 1.f);
    float4 a = make_float4(0.f, 0.f, 0.f, 0.f);

    float4 va[8], vb[8];
    FLOADB(va, 0);
    FLOADB(vb, 1);
    FCACC(va, 0);
    FLOADB(va, 2);
    FCACC(vb, 1);
    FLOADB(vb, 3);
    FCACC(va, 2);
    FCACC(vb, 3);

    const int slice = (seg < 4) ? (4 + seg) : (6 + seg);   // 4..7, 10..13
    ((float4*)ws)[(size_t)slice * BH4 + q] = a;
}

// ---------------------------------------------------------------------------
// Pure shift copy: hc1_flat[i] = ht_flat[BH + i], i in [0, 255*BH).
// m13-shaped: 4080 blocks x 256 threads x 8 float4, plain stores.
// Runs right after mega_A so reads hit L3 (ht just streamed).
// ---------------------------------------------------------------------------
__global__ __launch_bounds__(256, 8) void k_copy(
    const float4* __restrict__ ht4, float4* __restrict__ hc14)
{
    const size_t base = (size_t)blockIdx.x * 2048 + threadIdx.x;
    const float4* src = ht4 + BH4 + base;
    float4* dst = hc14 + base;
    float4 v[8];
    #pragma unroll
    for (int u = 0; u < 8; ++u) v[u] = src[(size_t)u * 256];
    #pragma unroll
    for (int u = 0; u < 8; ++u) dst[(size_t)u * 256] = v[u];
}

// finalize: recompute 7 segment-prefix products from dv (224-step chain),
// combine 8 segment accs, h-parts reduce, hn = tanh(.)*(1-z) - acc.
__global__ __launch_bounds__(256) void k_finalize(
    const float4* __restrict__ dv4, const float4* __restrict__ ws4,
    const float4* __restrict__ bh, const float4* __restrict__ zb4,
    float4* hc1_4, float4* __restrict__ hn_out)
{
    __shared__ float s_inv[224], s_tinv[224];
    const int tid = threadIdx.x;
    if (tid < 224) { const float fi = 1.0f / (float)(tid + 1);
                     s_inv[tid] = fi; s_tinv[tid] = (float)tid * fi; }
    __syncthreads();

    const int g = blockIdx.x * 256 + tid;
    const int n = g & (H4 - 1);
    const float4 d = dv4[g];

    float4 acc = ws4[(size_t)4 * BH4 + g];           // segment 0 acc
    float4 c = make_float4(1.f, 1.f, 1.f, 1.f);
    #pragma unroll
    for (int sgm = 1; sgm < 8; ++sgm) {
        #pragma unroll
        for (int t = (sgm - 1) * 32; t < sgm * 32; ++t) {
            const float iv = s_inv[t], tv = s_tinv[t];
            c.x *= fmaf(-d.x, iv, tv); c.y *= fmaf(-d.y, iv, tv);
            c.z *= fmaf(-d.z, iv, tv); c.w *= fmaf(-d.w, iv, tv);
        }
        const int sl = (sgm < 4) ? (4 + sgm) : (6 + sgm);
        const float4 ai = ws4[(size_t)sl * BH4 + g];
        acc.x = fmaf(c.x, ai.x, acc.x); acc.y = fmaf(c.y, ai.y, acc.y);
        acc.z = fmaf(c.z, ai.z, acc.z); acc.w = fmaf(c.w, ai.w, acc.w);
    }

    float4 hs = bh[n];
    #pragma unroll
    for (int s = 0; s < 4; ++s) { const float4 p = ws4[(size_t)s * BH4 + g];
        hs.x += p.x; hs.y += p.y; hs.z += p.z; hs.w += p.w; }
    const float4 z = zb4[g];

    float4 hn;
    hn.x = tanh_fast(hs.x) * (1.0f - z.x) - acc.x;
    hn.y = tanh_fast(hs.y) * (1.0f - z.y) - acc.y;
    hn.z = tanh_fast(hs.z) * (1.0f - z.z) - acc.z;
    hn.w = tanh_fast(hs.w) * (1.0f - z.w) - acc.w;
    hn_out[g] = hn;
    hc1_4[(size_t)255 * BH4 + g] = hn;
}

__global__ __launch_bounds__(256) void k_gemm_o(
    const float* __restrict__ hn, const float* __restrict__ Wo,
    float* __restrict__ parts, int chunk)
{
    __shared__ float As[BK][BM + 4];
    __shared__ float Ws[BK][BN + 4];
    const int s = blockIdx.z, ks = s * chunk;
    gemm64<false>(As, Ws, hn + ks, nullptr, Wo, 512, ks,
                  blockIdx.y * BM, blockIdx.x * BN, chunk / BK, parts + (size_t)s * BH);
}

// no __restrict__: fallback path calls with parts == out (same-thread RMW)
__global__ __launch_bounds__(256) void k_reduce_o(
    const float4* parts, const float4* __restrict__ bo, float4* out, int NS)
{
    const int g = blockIdx.x * 256 + threadIdx.x;
    float4 v = bo[g & (H4 - 1)];
    for (int s = 0; s < NS; ++s) { const float4 p = parts[(size_t)s * BH4 + g];
        v.x += p.x; v.y += p.y; v.z += p.z; v.w += p.w; }
    out[g] = v;
}

// ------------------------- fallback-only kernels ---------------------------
__global__ __launch_bounds__(256) void k_reduce_rz(
    const float4* __restrict__ parts, const float4* __restrict__ br,
    const float4* __restrict__ bz, float4* __restrict__ rb, float4* __restrict__ zb)
{
    const int g = blockIdx.x * 256 + threadIdx.x;
    const int n = g & (H4 - 1);
    float4 r = br[n], z = bz[n];
    #pragma unroll
    for (int s = 0; s < 4; ++s) { const float4 p = parts[(size_t)s * BH4 + g];
        r.x += p.x; r.y += p.y; r.z += p.z; r.w += p.w; }
    #pragma unroll
    for (int s = 4; s < 8; ++s) { const float4 p = parts[(size_t)s * BH4 + g];
        z.x += p.x; z.y += p.y; z.z += p.z; z.w += p.w; }
    rb[g] = sig4(r); zb[g] = sig4(z);
}

__global__ __launch_bounds__(256) void k_gemm_h(
    const float* __restrict__ sample, const float* __restrict__ hidden,
    const float* __restrict__ rb, const float* __restrict__ Wh,
    float* __restrict__ parts)
{
    __shared__ float As[BK][BM + 4];
    __shared__ float Ws[BK][BN + 4];
    const int s = blockIdx.z, ks = s << 8;
    if (ks < 512)
        gemm64<false>(As, Ws, sample + ks, nullptr, Wh, 1024, ks,
                      blockIdx.y * BM, blockIdx.x * BN, 16, parts + (size_t)s * BH);
    else
        gemm64<true>(As, Ws, hidden + (ks - 512), rb + (ks - 512), Wh, 1024, ks,
                     blockIdx.y * BM, blockIdx.x * BN, 16, parts + (size_t)s * BH);
}

__global__ __launch_bounds__(256) void k_filter_full(
    const float* __restrict__ ht, const float* dparts, const float* __restrict__ bd,
    const float* zbuf, const float* hparts, const float* __restrict__ bh,
    float* hc1, float* __restrict__ dv_out, float* __restrict__ hn_out)
{
    __shared__ float s_inv[KF], s_tinv[KF];
    const int tid = threadIdx.x;
    const float fi = 1.0f / (float)(tid + 1);
    s_inv[tid] = fi; s_tinv[tid] = (float)tid * fi;
    __syncthreads();

    const int g = blockIdx.x * 256 + tid;
    const int n = g & (H_ - 1);
    float sd = bd[n];
    #pragma unroll
    for (int s = 0; s < 6; ++s) sd += dparts[(size_t)s * BH + g];
    const float d = 0.5f * sigmoidf_(sd);
    dv_out[g] = d;
    float sh = bh[n];
    #pragma unroll
    for (int s = 0; s < 4; ++s) sh += hparts[(size_t)s * BH + g];
    const float z = zbuf[g];

    float c = 1.0f, acc = 0.0f;
    #pragma unroll 16
    for (int t = 0; t < KF; ++t) {
        const int k = KF - 1 - t;
        const float v = ht[(size_t)k * BH + g];
        c *= fmaf(-d, s_inv[t], s_tinv[t]);
        acc = fmaf(v, c, acc);
        if (k >= 1) hc1[(size_t)(k - 1) * BH + g] = v;
    }
    const float hn = tanh_fast(sh) * (1.0f - z) - acc;
    hc1[(size_t)(KF - 1) * BH + g] = hn;
    hn_out[g] = hn;
}

extern "C" void kernel_launch(void* const* d_in, const int* in_sizes, int n_in,
                              void* d_out, int out_size, void* d_ws, size_t ws_size,
                              hipStream_t stream)
{
    const float* sample = (const float*)d_in[0];
    const float* hidden = (const float*)d_in[1];
    const float* ht     = (const float*)d_in[2];
    const float* d0     = (const float*)d_in[3];
    const float* Wd = (const float*)d_in[4];
    const float* bd = (const float*)d_in[5];
    const float* Wr = (const float*)d_in[6];
    const float* br = (const float*)d_in[7];
    const float* Wz = (const float*)d_in[8];
    const float* bz = (const float*)d_in[9];
    const float* Wh = (const float*)d_in[10];
    const float* bh = (const float*)d_in[11];
    const float* Wo = (const float*)d_in[12];
    const float* bo = (const float*)d_in[13];

    float* out     = (float*)d_out;
    float* out_o   = out;
    float* out_hn  = out + BH;
    float* out_hc1 = out + 2 * BH;
    float* out_dv  = out + 2 * BH + (size_t)KF * BH;

    const size_t slice = BH;
    const size_t need = 14ull * slice * sizeof(float);

    if (ws_size >= need) {
        float* ws = (float*)d_ws;
        // ws slices: [0..3] r-parts -> h-parts -> o-parts
        //            [4..7] z-parts -> filter accs 0..3
        //            [8] rb, [9] zb, [10..13] filter accs 4..7
        // d-parts -> hc1 slices 0..5 (dead after k_dv, overwritten by copy).
        float* rb = ws + 8 * slice;
        float* zb = ws + 9 * slice;

        k_gemm_drz<<<dim3(8, 4, 14), 256, 0, stream>>>(sample, hidden, d0,
                                                       Wd, Wr, Wz, out_hc1, ws);
        k_dv<<<dim3(128), 256, 0, stream>>>(
            (const float4*)out_hc1, (const float4*)bd,
            (const float4*)ws, (const float4*)br, (const float4*)bz,
            (float4*)out_dv, (float4*)rb, (float4*)zb);
        k_mega_A<<<dim3(1152), 256, 0, stream>>>(
            (const float4*)ht, (const float4*)out_dv, sample, hidden, rb, Wh, ws);
        k_copy<<<dim3(4080), 256, 0, stream>>>(
            (const float4*)ht, (float4*)out_hc1);
        k_finalize<<<dim3(128), 256, 0, stream>>>(
            (const float4*)out_dv, (const float4*)ws,
            (const float4*)bh, (const float4*)zb,
            (float4*)out_hc1, (float4*)out_hn);
        k_gemm_o<<<dim3(8, 4, 4), 256, 0, stream>>>(out_hn, Wo, ws, 128);
        k_reduce_o<<<dim3(128), 256, 0, stream>>>((const float4*)ws,
                                                  (const float4*)bo,
                                                  (float4*)out_o, 4);
    } else {
        // serial fallback, all scratch = dead hc1 slices
        float* sl = out_hc1;
        k_gemm_drz<<<dim3(8, 4, 14), 256, 0, stream>>>(sample, hidden, d0,
                                                       Wd, Wr, Wz, sl, sl + 6 * slice);
        k_reduce_rz<<<dim3(128), 256, 0, stream>>>((const float4*)(sl + 6 * slice),
                                                   (const float4*)br, (const float4*)bz,
                                                   (float4*)(sl + 14 * slice),
                                                   (float4*)(sl + 15 * slice));
        k_gemm_h<<<dim3(8, 4, 4), 256, 0, stream>>>(sample, hidden, sl + 14 * slice, Wh,
                                                    sl + 16 * slice);
        k_filter_full<<<dim3(512), 256, 0, stream>>>(ht, sl, bd, sl + 15 * slice,
                                                     sl + 16 * slice, bh,
                                                     out_hc1, out_dv, out_hn);
        k_gemm_o<<<dim3(8, 4, 1), 256, 0, stream>>>(out_hn, Wo, out_o, 512);
        k_reduce_o<<<dim3(128), 256, 0, stream>>>((const float4*)out_o, (const float4*)bo,
                                                  (float4*)out_o, 1);
    }
}

// Round 13
// 103.777 us; speedup vs baseline: 1.0596x; 1.0596x over previous
//
#include <hip/hip_runtime.h>
#include <cstddef>

#define B_ 256
#define H_ 512
#define KF 256
#define BH 131072    // B_*H_
#define BH4 32768    // BH/4
#define H4 128       // H_/4

#define BM 64
#define BN 64
#define BK 16

typedef float nf4 __attribute__((ext_vector_type(4)));

__device__ __forceinline__ float sigmoidf_(float x) { return 1.0f / (1.0f + __expf(-x)); }
__device__ __forceinline__ float tanh_fast(float x) { return 2.0f / (1.0f + __expf(-2.0f * x)) - 1.0f; }
__device__ __forceinline__ float4 sig4(float4 v) {
    return make_float4(sigmoidf_(v.x), sigmoidf_(v.y), sigmoidf_(v.z), sigmoidf_(v.w));
}
__device__ __forceinline__ void cupd(float4& c, const float4 d, float iv, float tv) {
    c.x *= fmaf(-d.x, iv, tv); c.y *= fmaf(-d.y, iv, tv);
    c.z *= fmaf(-d.z, iv, tv); c.w *= fmaf(-d.w, iv, tv);
}
__device__ __forceinline__ void afma(float4& a, const float4 v, const float4 c) {
    a.x = fmaf(v.x, c.x, a.x); a.y = fmaf(v.y, c.y, a.y);
    a.z = fmaf(v.z, c.z, a.z); a.w = fmaf(v.w, c.w, a.w);
}

#define MAC_LOOP()                                                         \
    _Pragma("unroll")                                                      \
    for (int kk = 0; kk < BK; ++kk) {                                      \
        const float4 a = *(const float4*)&As[kk][ty << 2];                 \
        const float4 w = *(const float4*)&Ws[kk][tx << 2];                 \
        const float a4[4] = {a.x, a.y, a.z, a.w};                          \
        const float w4[4] = {w.x, w.y, w.z, w.w};                          \
        _Pragma("unroll")                                                  \
        for (int i = 0; i < 4; ++i)                                        \
            _Pragma("unroll")                                              \
            for (int j = 0; j < 4; ++j)                                    \
                acc[i][j] = fmaf(a4[i], w4[j], acc[i][j]);                 \
    }

// ---------------------------------------------------------------------------
// 64x64-tile split-K partial GEMM over a K-chunk, register double-stage.
// ---------------------------------------------------------------------------
template<bool MUL>
__device__ __forceinline__ void gemm64(
    float (*As)[BM + 4], float (*Ws)[BN + 4],
    const float* __restrict__ abase, const float* __restrict__ rbase,
    const float* __restrict__ W, int Ktot, int ks,
    int bm, int bn, int nIter, float* __restrict__ p)
{
    const int tid = threadIdx.x;
    const int ty = tid >> 4, tx = tid & 15;
    const int lrow = tid >> 2, lcol = (tid & 3) << 2;
    const float* aptr = abase + (bm + lrow) * 512 + lcol;
    const float* rptr = MUL ? rbase + (bm + lrow) * 512 + lcol : nullptr;
    const float* wptr = W + (size_t)(bn + lrow) * Ktot + ks + lcol;

    float acc[4][4] = {};
    float4 av = *(const float4*)aptr;
    if (MUL) { const float4 rv = *(const float4*)rptr;
               av.x *= rv.x; av.y *= rv.y; av.z *= rv.z; av.w *= rv.w; }
    float4 wv = *(const float4*)wptr;

    for (int it = 0; it < nIter; ++it) {
        __syncthreads();
        As[lcol + 0][lrow] = av.x; As[lcol + 1][lrow] = av.y;
        As[lcol + 2][lrow] = av.z; As[lcol + 3][lrow] = av.w;
        Ws[lcol + 0][lrow] = wv.x; Ws[lcol + 1][lrow] = wv.y;
        Ws[lcol + 2][lrow] = wv.z; Ws[lcol + 3][lrow] = wv.w;
        __syncthreads();
        if (it < nIter - 1) {
            av = *(const float4*)(aptr + (it + 1) * BK);
            if (MUL) { const float4 rv = *(const float4*)(rptr + (it + 1) * BK);
                       av.x *= rv.x; av.y *= rv.y; av.z *= rv.z; av.w *= rv.w; }
            wv = *(const float4*)(wptr + (it + 1) * BK);
        }
        MAC_LOOP();
    }
    #pragma unroll
    for (int i = 0; i < 4; ++i) {
        const int m = bm + (ty << 2) + i;
        #pragma unroll
        for (int j = 0; j < 4; ++j)
            p[m * 512 + bn + (tx << 2) + j] = acc[i][j];
    }
}

// All input-only GEMM parts in one launch. z 0..5: d splits (K=1536) ->
// dbase slices 0..5 (hc1 dead space); z 6..13: r (0..3) / z (4..7) -> rzbase.
__global__ __launch_bounds__(256) void k_gemm_drz(
    const float* __restrict__ sample, const float* __restrict__ hidden,
    const float* __restrict__ d0,
    const float* __restrict__ Wd, const float* __restrict__ Wr,
    const float* __restrict__ Wz,
    float* __restrict__ dbase, float* __restrict__ rzbase)
{
    __shared__ float As[BK][BM + 4];
    __shared__ float Ws[BK][BN + 4];
    const int z = blockIdx.z;
    if (z < 6) {
        const int ks = z << 8, seg = ks >> 9;
        const float* ab = (seg == 0 ? sample : (seg == 1 ? hidden : d0)) + (ks & 511);
        gemm64<false>(As, Ws, ab, nullptr, Wd, 1536, ks,
                      blockIdx.y * BM, blockIdx.x * BN, 16, dbase + (size_t)z * BH);
    } else {
        const int id = z - 6, gz = id >> 2, s = id & 3, ks = s << 8;
        const float* ab = (ks < 512 ? sample + ks : hidden + (ks - 512));
        gemm64<false>(As, Ws, ab, nullptr, gz ? Wz : Wr, 1024, ks,
                      blockIdx.y * BM, blockIdx.x * BN, 16, rzbase + (size_t)id * BH);
    }
}

// dv/rb/zb reduce: consumes d-parts (hc1 slices 0..5, dead afterwards) and
// r/z parts (ws 0..7, dead afterwards -> reused for h-parts and accs).
__global__ __launch_bounds__(256) void k_dv(
    const float4* __restrict__ dparts, const float4* __restrict__ bd,
    const float4* __restrict__ rzparts, const float4* __restrict__ br,
    const float4* __restrict__ bz,
    float4* __restrict__ dv4, float4* __restrict__ rb4, float4* __restrict__ zb4)
{
    const int g = blockIdx.x * 256 + threadIdx.x;
    const int n = g & (H4 - 1);
    float4 sd = bd[n], sr = br[n], sz = bz[n];
    #pragma unroll
    for (int s = 0; s < 6; ++s) { const float4 p = dparts[(size_t)s * BH4 + g];
        sd.x += p.x; sd.y += p.y; sd.z += p.z; sd.w += p.w; }
    #pragma unroll
    for (int s = 0; s < 4; ++s) { const float4 p = rzparts[(size_t)s * BH4 + g];
        sr.x += p.x; sr.y += p.y; sr.z += p.z; sr.w += p.w; }
    #pragma unroll
    for (int s = 4; s < 8; ++s) { const float4 p = rzparts[(size_t)s * BH4 + g];
        sz.x += p.x; sz.y += p.y; sz.z += p.z; sz.w += p.w; }
    const float4 d = sig4(sd);
    dv4[g] = make_float4(0.5f * d.x, 0.5f * d.y, 0.5f * d.z, 0.5f * d.w);
    rb4[g] = sig4(sr);
    zb4[g] = sig4(sz);
}

// ---------------------------------------------------------------------------
// mega: bid<128 = h-GEMM -> ws slices 0..3;
//       bid 128..639 = PAGE-LOCAL filter+shift: each block owns an 8KB
// contiguous column chunk (64 chunks/slice) of one of 8 K-segments
// (32 k-steps each). Per k-step the block reads 8KB contiguous from slice k,
// accumulates the segment-local cumprod weight, NT-stores 8KB contiguous to
// slice k-1. 2-deep prefetch pipeline. All transactions are contiguous
// bursts within a slice (vs prior variants' 4KB-per-slice hops across
// 512KB-strided slices) -> DRAM page locality.
// Segment s: t = 32s..32s+31, k = 255-t, local cumprod from 1;
// acc_s -> ws slice (s<4 ? 4+s : 6+s). k=0 store lands one slice BELOW hc1
// (= out_hn region, overwritten by k_finalize) -> branch-free.
// ---------------------------------------------------------------------------
__global__ __launch_bounds__(256, 4) void k_mega(
    const float4* __restrict__ ht4, const float4* __restrict__ dv4,
    const float* __restrict__ sample, const float* __restrict__ hidden,
    const float* __restrict__ rb, const float* __restrict__ Wh,
    float* __restrict__ ws, float4* __restrict__ hc14)
{
    const int bid = blockIdx.x;
    const int tid = threadIdx.x;
    if (bid < 128) {
        __shared__ float As[BK][BM + 4];
        __shared__ float Wsh[BK][BN + 4];
        const int s = bid >> 5, t2 = bid & 31;
        const int bn = (t2 >> 2) << 6, bm = (t2 & 3) << 6, ks = s << 8;
        if (ks < 512)
            gemm64<false>(As, Wsh, sample + ks, nullptr, Wh, 1024, ks, bm, bn, 16,
                          ws + (size_t)s * BH);
        else
            gemm64<true>(As, Wsh, hidden + (ks - 512), rb + (ks - 512), Wh, 1024, ks,
                         bm, bn, 16, ws + (size_t)s * BH);
        return;
    }

    __shared__ float s_inv[KF], s_tinv[KF];
    {
        const float fi = 1.0f / (float)(tid + 1);
        s_inv[tid] = fi; s_tinv[tid] = (float)tid * fi;
    }
    __syncthreads();

    const int fidx = bid - 128;                  // 0..511
    const int seg  = fidx >> 6;                  // 0..7
    const int q    = ((fidx & 63) << 9) + tid;   // chunk*512 + tid (float4 idx)
    const int t0   = seg << 5;

    const float4 d0 = dv4[q];
    const float4 d1 = dv4[q + 256];

    const float4* ldp = ht4  + (size_t)(255 - t0) * BH4 + q;
    float4*       stp = hc14 + (ptrdiff_t)(254 - t0) * BH4 + q;

    float4 c0 = make_float4(1.f, 1.f, 1.f, 1.f), c1 = c0;
    float4 a0 = make_float4(0.f, 0.f, 0.f, 0.f), a1 = a0;

    float4 va0 = ldp[0], va1 = ldp[256];

    #pragma unroll
    for (int j = 0; j < 32; j += 2) {
        // prefetch k-step j+1 (always valid: j <= 30)
        float4 vb0 = ldp[-(ptrdiff_t)(j + 1) * BH4];
        float4 vb1 = ldp[-(ptrdiff_t)(j + 1) * BH4 + 256];
        {   // process step j (t = t0+j)
            const float iv = s_inv[t0 + j], tv = s_tinv[t0 + j];
            cupd(c0, d0, iv, tv); cupd(c1, d1, iv, tv);
            afma(a0, va0, c0);    afma(a1, va1, c1);
            __builtin_nontemporal_store(*(const nf4*)&va0,
                (nf4*)(stp - (ptrdiff_t)j * BH4));
            __builtin_nontemporal_store(*(const nf4*)&va1,
                (nf4*)(stp - (ptrdiff_t)j * BH4 + 256));
        }
        if (j + 2 < 32) {   // prefetch k-step j+2
            va0 = ldp[-(ptrdiff_t)(j + 2) * BH4];
            va1 = ldp[-(ptrdiff_t)(j + 2) * BH4 + 256];
        }
        {   // process step j+1
            const float iv = s_inv[t0 + j + 1], tv = s_tinv[t0 + j + 1];
            cupd(c0, d0, iv, tv); cupd(c1, d1, iv, tv);
            afma(a0, vb0, c0);    afma(a1, vb1, c1);
            __builtin_nontemporal_store(*(const nf4*)&vb0,
                (nf4*)(stp - (ptrdiff_t)(j + 1) * BH4));
            __builtin_nontemporal_store(*(const nf4*)&vb1,
                (nf4*)(stp - (ptrdiff_t)(j + 1) * BH4 + 256));
        }
    }

    const int slice = (seg < 4) ? (4 + seg) : (6 + seg);   // 4..7, 10..13
    ((float4*)ws)[(size_t)slice * BH4 + q] = a0;
    ((float4*)ws)[(size_t)slice * BH4 + q + 256] = a1;
}

// finalize: recompute 7 segment-prefix products from dv (224-step chain),
// combine 8 segment accs, h-parts reduce, hn = tanh(.)*(1-z) - acc.
__global__ __launch_bounds__(256) void k_finalize(
    const float4* __restrict__ dv4, const float4* __restrict__ ws4,
    const float4* __restrict__ bh, const float4* __restrict__ zb4,
    float4* hc1_4, float4* __restrict__ hn_out)
{
    __shared__ float s_inv[224], s_tinv[224];
    const int tid = threadIdx.x;
    if (tid < 224) { const float fi = 1.0f / (float)(tid + 1);
                     s_inv[tid] = fi; s_tinv[tid] = (float)tid * fi; }
    __syncthreads();

    const int g = blockIdx.x * 256 + tid;
    const int n = g & (H4 - 1);
    const float4 d = dv4[g];

    float4 acc = ws4[(size_t)4 * BH4 + g];           // segment 0 acc
    float4 c = make_float4(1.f, 1.f, 1.f, 1.f);
    #pragma unroll
    for (int sgm = 1; sgm < 8; ++sgm) {
        #pragma unroll
        for (int t = (sgm - 1) * 32; t < sgm * 32; ++t) {
            const float iv = s_inv[t], tv = s_tinv[t];
            cupd(c, d, iv, tv);
        }
        const int sl = (sgm < 4) ? (4 + sgm) : (6 + sgm);
        const float4 ai = ws4[(size_t)sl * BH4 + g];
        afma(acc, ai, c);
    }

    float4 hs = bh[n];
    #pragma unroll
    for (int s = 0; s < 4; ++s) { const float4 p = ws4[(size_t)s * BH4 + g];
        hs.x += p.x; hs.y += p.y; hs.z += p.z; hs.w += p.w; }
    const float4 z = zb4[g];

    float4 hn;
    hn.x = tanh_fast(hs.x) * (1.0f - z.x) - acc.x;
    hn.y = tanh_fast(hs.y) * (1.0f - z.y) - acc.y;
    hn.z = tanh_fast(hs.z) * (1.0f - z.z) - acc.z;
    hn.w = tanh_fast(hs.w) * (1.0f - z.w) - acc.w;
    hn_out[g] = hn;
    hc1_4[(size_t)255 * BH4 + g] = hn;
}

__global__ __launch_bounds__(256) void k_gemm_o(
    const float* __restrict__ hn, const float* __restrict__ Wo,
    float* __restrict__ parts, int chunk)
{
    __shared__ float As[BK][BM + 4];
    __shared__ float Ws[BK][BN + 4];
    const int s = blockIdx.z, ks = s * chunk;
    gemm64<false>(As, Ws, hn + ks, nullptr, Wo, 512, ks,
                  blockIdx.y * BM, blockIdx.x * BN, chunk / BK, parts + (size_t)s * BH);
}

// no __restrict__: fallback path calls with parts == out (same-thread RMW)
__global__ __launch_bounds__(256) void k_reduce_o(
    const float4* parts, const float4* __restrict__ bo, float4* out, int NS)
{
    const int g = blockIdx.x * 256 + threadIdx.x;
    float4 v = bo[g & (H4 - 1)];
    for (int s = 0; s < NS; ++s) { const float4 p = parts[(size_t)s * BH4 + g];
        v.x += p.x; v.y += p.y; v.z += p.z; v.w += p.w; }
    out[g] = v;
}

// ------------------------- fallback-only kernels ---------------------------
__global__ __launch_bounds__(256) void k_reduce_rz(
    const float4* __restrict__ parts, const float4* __restrict__ br,
    const float4* __restrict__ bz, float4* __restrict__ rb, float4* __restrict__ zb)
{
    const int g = blockIdx.x * 256 + threadIdx.x;
    const int n = g & (H4 - 1);
    float4 r = br[n], z = bz[n];
    #pragma unroll
    for (int s = 0; s < 4; ++s) { const float4 p = parts[(size_t)s * BH4 + g];
        r.x += p.x; r.y += p.y; r.z += p.z; r.w += p.w; }
    #pragma unroll
    for (int s = 4; s < 8; ++s) { const float4 p = parts[(size_t)s * BH4 + g];
        z.x += p.x; z.y += p.y; z.z += p.z; z.w += p.w; }
    rb[g] = sig4(r); zb[g] = sig4(z);
}

__global__ __launch_bounds__(256) void k_gemm_h(
    const float* __restrict__ sample, const float* __restrict__ hidden,
    const float* __restrict__ rb, const float* __restrict__ Wh,
    float* __restrict__ parts)
{
    __shared__ float As[BK][BM + 4];
    __shared__ float Ws[BK][BN + 4];
    const int s = blockIdx.z, ks = s << 8;
    if (ks < 512)
        gemm64<false>(As, Ws, sample + ks, nullptr, Wh, 1024, ks,
                      blockIdx.y * BM, blockIdx.x * BN, 16, parts + (size_t)s * BH);
    else
        gemm64<true>(As, Ws, hidden + (ks - 512), rb + (ks - 512), Wh, 1024, ks,
                     blockIdx.y * BM, blockIdx.x * BN, 16, parts + (size_t)s * BH);
}

__global__ __launch_bounds__(256) void k_filter_full(
    const float* __restrict__ ht, const float* dparts, const float* __restrict__ bd,
    const float* zbuf, const float* hparts, const float* __restrict__ bh,
    float* hc1, float* __restrict__ dv_out, float* __restrict__ hn_out)
{
    __shared__ float s_inv[KF], s_tinv[KF];
    const int tid = threadIdx.x;
    const float fi = 1.0f / (float)(tid + 1);
    s_inv[tid] = fi; s_tinv[tid] = (float)tid * fi;
    __syncthreads();

    const int g = blockIdx.x * 256 + tid;
    const int n = g & (H_ - 1);
    float sd = bd[n];
    #pragma unroll
    for (int s = 0; s < 6; ++s) sd += dparts[(size_t)s * BH + g];
    const float d = 0.5f * sigmoidf_(sd);
    dv_out[g] = d;
    float sh = bh[n];
    #pragma unroll
    for (int s = 0; s < 4; ++s) sh += hparts[(size_t)s * BH + g];
    const float z = zbuf[g];

    float c = 1.0f, acc = 0.0f;
    #pragma unroll 16
    for (int t = 0; t < KF; ++t) {
        const int k = KF - 1 - t;
        const float v = ht[(size_t)k * BH + g];
        c *= fmaf(-d, s_inv[t], s_tinv[t]);
        acc = fmaf(v, c, acc);
        if (k >= 1) hc1[(size_t)(k - 1) * BH + g] = v;
    }
    const float hn = tanh_fast(sh) * (1.0f - z) - acc;
    hc1[(size_t)(KF - 1) * BH + g] = hn;
    hn_out[g] = hn;
}

extern "C" void kernel_launch(void* const* d_in, const int* in_sizes, int n_in,
                              void* d_out, int out_size, void* d_ws, size_t ws_size,
                              hipStream_t stream)
{
    const float* sample = (const float*)d_in[0];
    const float* hidden = (const float*)d_in[1];
    const float* ht     = (const float*)d_in[2];
    const float* d0     = (const float*)d_in[3];
    const float* Wd = (const float*)d_in[4];
    const float* bd = (const float*)d_in[5];
    const float* Wr = (const float*)d_in[6];
    const float* br = (const float*)d_in[7];
    const float* Wz = (const float*)d_in[8];
    const float* bz = (const float*)d_in[9];
    const float* Wh = (const float*)d_in[10];
    const float* bh = (const float*)d_in[11];
    const float* Wo = (const float*)d_in[12];
    const float* bo = (const float*)d_in[13];

    float* out     = (float*)d_out;
    float* out_o   = out;
    float* out_hn  = out + BH;
    float* out_hc1 = out + 2 * BH;
    float* out_dv  = out + 2 * BH + (size_t)KF * BH;

    const size_t slice = BH;
    const size_t need = 14ull * slice * sizeof(float);

    if (ws_size >= need) {
        float* ws = (float*)d_ws;
        // ws slices: [0..3] r-parts -> h-parts -> o-parts
        //            [4..7] z-parts -> filter accs 0..3
        //            [8] rb, [9] zb, [10..13] filter accs 4..7
        // d-parts -> hc1 slices 0..5 (dead after k_dv, overwritten by filter).
        float* rb = ws + 8 * slice;
        float* zb = ws + 9 * slice;

        k_gemm_drz<<<dim3(8, 4, 14), 256, 0, stream>>>(sample, hidden, d0,
                                                       Wd, Wr, Wz, out_hc1, ws);
        k_dv<<<dim3(128), 256, 0, stream>>>(
            (const float4*)out_hc1, (const float4*)bd,
            (const float4*)ws, (const float4*)br, (const float4*)bz,
            (float4*)out_dv, (float4*)rb, (float4*)zb);
        k_mega<<<dim3(640), 256, 0, stream>>>(
            (const float4*)ht, (const float4*)out_dv, sample, hidden, rb, Wh,
            ws, (float4*)out_hc1);
        k_finalize<<<dim3(128), 256, 0, stream>>>(
            (const float4*)out_dv, (const float4*)ws,
            (const float4*)bh, (const float4*)zb,
            (float4*)out_hc1, (float4*)out_hn);
        k_gemm_o<<<dim3(8, 4, 4), 256, 0, stream>>>(out_hn, Wo, ws, 128);
        k_reduce_o<<<dim3(128), 256, 0, stream>>>((const float4*)ws,
                                                  (const float4*)bo,
                                                  (float4*)out_o, 4);
    } else {
        // serial fallback, all scratch = dead hc1 slices
        float* sl = out_hc1;
        k_gemm_drz<<<dim3(8, 4, 14), 256, 0, stream>>>(sample, hidden, d0,
                                                       Wd, Wr, Wz, sl, sl + 6 * slice);
        k_reduce_rz<<<dim3(128), 256, 0, stream>>>((const float4*)(sl + 6 * slice),
                                                   (const float4*)br, (const float4*)bz,
                                                   (float4*)(sl + 14 * slice),
                                                   (float4*)(sl + 15 * slice));
        k_gemm_h<<<dim3(8, 4, 4), 256, 0, stream>>>(sample, hidden, sl + 14 * slice, Wh,
                                                    sl + 16 * slice);
        k_filter_full<<<dim3(512), 256, 0, stream>>>(ht, sl, bd, sl + 15 * slice,
                                                     sl + 16 * slice, bh,
                                                     out_hc1, out_dv, out_hn);
        k_gemm_o<<<dim3(8, 4, 1), 256, 0, stream>>>(out_hn, Wo, out_o, 512);
        k_reduce_o<<<dim3(128), 256, 0, stream>>>((const float4*)out_o, (const float4*)bo,
                                                  (float4*)out_o, 1);
    }
}

// Round 14
// 85.201 us; speedup vs baseline: 1.2906x; 1.2180x over previous
//
#include <hip/hip_runtime.h>
#include <cstddef>

#define B_ 256
#define H_ 512
#define KF 256
#define BH 131072    // B_*H_
#define BH4 32768    // BH/4
#define H4 128       // H_/4

#define BM 64
#define BN 64
#define BK 16

typedef float nf4 __attribute__((ext_vector_type(4)));

__device__ __forceinline__ float sigmoidf_(float x) { return 1.0f / (1.0f + __expf(-x)); }
__device__ __forceinline__ float tanh_fast(float x) { return 2.0f / (1.0f + __expf(-2.0f * x)) - 1.0f; }
__device__ __forceinline__ float4 sig4(float4 v) {
    return make_float4(sigmoidf_(v.x), sigmoidf_(v.y), sigmoidf_(v.z), sigmoidf_(v.w));
}
__device__ __forceinline__ void cupd(float4& c, const float4 d, float iv, float tv) {
    c.x *= fmaf(-d.x, iv, tv); c.y *= fmaf(-d.y, iv, tv);
    c.z *= fmaf(-d.z, iv, tv); c.w *= fmaf(-d.w, iv, tv);
}
__device__ __forceinline__ void afma(float4& a, const float4 v, const float4 c) {
    a.x = fmaf(v.x, c.x, a.x); a.y = fmaf(v.y, c.y, a.y);
    a.z = fmaf(v.z, c.z, a.z); a.w = fmaf(v.w, c.w, a.w);
}

#define MAC_LOOP()                                                         \
    _Pragma("unroll")                                                      \
    for (int kk = 0; kk < BK; ++kk) {                                      \
        const float4 a = *(const float4*)&As[kk][ty << 2];                 \
        const float4 w = *(const float4*)&Ws[kk][tx << 2];                 \
        const float a4[4] = {a.x, a.y, a.z, a.w};                          \
        const float w4[4] = {w.x, w.y, w.z, w.w};                          \
        _Pragma("unroll")                                                  \
        for (int i = 0; i < 4; ++i)                                        \
            _Pragma("unroll")                                              \
            for (int j = 0; j < 4; ++j)                                    \
                acc[i][j] = fmaf(a4[i], w4[j], acc[i][j]);                 \
    }

// ---------------------------------------------------------------------------
// 64x64-tile split-K partial GEMM over a K-chunk, register double-stage.
// ---------------------------------------------------------------------------
template<bool MUL>
__device__ __forceinline__ void gemm64(
    float (*As)[BM + 4], float (*Ws)[BN + 4],
    const float* __restrict__ abase, const float* __restrict__ rbase,
    const float* __restrict__ W, int Ktot, int ks,
    int bm, int bn, int nIter, float* __restrict__ p)
{
    const int tid = threadIdx.x;
    const int ty = tid >> 4, tx = tid & 15;
    const int lrow = tid >> 2, lcol = (tid & 3) << 2;
    const float* aptr = abase + (bm + lrow) * 512 + lcol;
    const float* rptr = MUL ? rbase + (bm + lrow) * 512 + lcol : nullptr;
    const float* wptr = W + (size_t)(bn + lrow) * Ktot + ks + lcol;

    float acc[4][4] = {};
    float4 av = *(const float4*)aptr;
    if (MUL) { const float4 rv = *(const float4*)rptr;
               av.x *= rv.x; av.y *= rv.y; av.z *= rv.z; av.w *= rv.w; }
    float4 wv = *(const float4*)wptr;

    for (int it = 0; it < nIter; ++it) {
        __syncthreads();
        As[lcol + 0][lrow] = av.x; As[lcol + 1][lrow] = av.y;
        As[lcol + 2][lrow] = av.z; As[lcol + 3][lrow] = av.w;
        Ws[lcol + 0][lrow] = wv.x; Ws[lcol + 1][lrow] = wv.y;
        Ws[lcol + 2][lrow] = wv.z; Ws[lcol + 3][lrow] = wv.w;
        __syncthreads();
        if (it < nIter - 1) {
            av = *(const float4*)(aptr + (it + 1) * BK);
            if (MUL) { const float4 rv = *(const float4*)(rptr + (it + 1) * BK);
                       av.x *= rv.x; av.y *= rv.y; av.z *= rv.z; av.w *= rv.w; }
            wv = *(const float4*)(wptr + (it + 1) * BK);
        }
        MAC_LOOP();
    }
    #pragma unroll
    for (int i = 0; i < 4; ++i) {
        const int m = bm + (ty << 2) + i;
        #pragma unroll
        for (int j = 0; j < 4; ++j)
            p[m * 512 + bn + (tx << 2) + j] = acc[i][j];
    }
}

// All input-only GEMM parts in one launch. z 0..5: d splits (K=1536) ->
// dbase slices 0..5 (hc1 dead space); z 6..13: r (0..3) / z (4..7) -> rzbase.
__global__ __launch_bounds__(256) void k_gemm_drz(
    const float* __restrict__ sample, const float* __restrict__ hidden,
    const float* __restrict__ d0,
    const float* __restrict__ Wd, const float* __restrict__ Wr,
    const float* __restrict__ Wz,
    float* __restrict__ dbase, float* __restrict__ rzbase)
{
    __shared__ float As[BK][BM + 4];
    __shared__ float Ws[BK][BN + 4];
    const int z = blockIdx.z;
    if (z < 6) {
        const int ks = z << 8, seg = ks >> 9;
        const float* ab = (seg == 0 ? sample : (seg == 1 ? hidden : d0)) + (ks & 511);
        gemm64<false>(As, Ws, ab, nullptr, Wd, 1536, ks,
                      blockIdx.y * BM, blockIdx.x * BN, 16, dbase + (size_t)z * BH);
    } else {
        const int id = z - 6, gz = id >> 2, s = id & 3, ks = s << 8;
        const float* ab = (ks < 512 ? sample + ks : hidden + (ks - 512));
        gemm64<false>(As, Ws, ab, nullptr, gz ? Wz : Wr, 1024, ks,
                      blockIdx.y * BM, blockIdx.x * BN, 16, rzbase + (size_t)id * BH);
    }
}

// dv/rb/zb reduce: consumes d-parts (hc1 slices 0..5, dead afterwards) and
// r/z parts (ws 0..7, dead afterwards -> reused for h-parts and accs).
__global__ __launch_bounds__(256) void k_dv(
    const float4* __restrict__ dparts, const float4* __restrict__ bd,
    const float4* __restrict__ rzparts, const float4* __restrict__ br,
    const float4* __restrict__ bz,
    float4* __restrict__ dv4, float4* __restrict__ rb4, float4* __restrict__ zb4)
{
    const int g = blockIdx.x * 256 + threadIdx.x;
    const int n = g & (H4 - 1);
    float4 sd = bd[n], sr = br[n], sz = bz[n];
    #pragma unroll
    for (int s = 0; s < 6; ++s) { const float4 p = dparts[(size_t)s * BH4 + g];
        sd.x += p.x; sd.y += p.y; sd.z += p.z; sd.w += p.w; }
    #pragma unroll
    for (int s = 0; s < 4; ++s) { const float4 p = rzparts[(size_t)s * BH4 + g];
        sr.x += p.x; sr.y += p.y; sr.z += p.z; sr.w += p.w; }
    #pragma unroll
    for (int s = 4; s < 8; ++s) { const float4 p = rzparts[(size_t)s * BH4 + g];
        sz.x += p.x; sz.y += p.y; sz.z += p.z; sz.w += p.w; }
    const float4 d = sig4(sd);
    dv4[g] = make_float4(0.5f * d.x, 0.5f * d.y, 0.5f * d.z, 0.5f * d.w);
    rb4[g] = sig4(sr);
    zb4[g] = sig4(sz);
}

// ---------------------------------------------------------------------------
// mega: bid<128 = h-GEMM -> ws slices 0..3;
//       bid 128..1151 = ASCENDING Horner filter+shift. Horner form:
// sum = f(0)*(ht[255] + f(1)*(ht[254] + ... + f(255)*ht[0])), f(m)=(m-d)/(m+1)
// evaluated inside-out: S = ht[j] + f(n+1)*S with j ascending 0->255.
// 8 segments x 128 blocks; segment s covers n in [32s, 32s+31], i.e. reads
// ht[224-32s .. 255-32s] ASCENDING (memory walks upward like the 7.2TB/s fill
// and 6.3TB/s m13 copy; all prior descending variants pinned at 2.5-3.5TB/s).
// Batch-8 double-buffered loads, NT stores to hc1[j-1] (also ascending).
// Segment Horner sums G_s -> ws slice (s<4 ? 4+s : 6+s); finalize recombines
// with prefix products F_s and acc_total = -d*acc_inner.
// Seg 7's j=0 store lands one slice BELOW hc1 (= out_hn region, overwritten
// by k_finalize) -> branch-free.
// ---------------------------------------------------------------------------
#define FLOADB(buf, b)                                                     \
    _Pragma("unroll")                                                      \
    for (int u = 0; u < 8; ++u)                                            \
        buf[u] = ld_base[(ptrdiff_t)((b) * 8 + u) * BH4];

#define FCSTORE(buf, b)                                                    \
    _Pragma("unroll")                                                      \
    for (int u = 0; u < 8; ++u) {                                          \
        const int idx = i0 - ((b) * 8 + u);                                \
        const float iv = s_inv[idx], tv = s_tinv[idx];                     \
        float4 f;                                                          \
        f.x = fmaf(-d.x, iv, tv); f.y = fmaf(-d.y, iv, tv);                \
        f.z = fmaf(-d.z, iv, tv); f.w = fmaf(-d.w, iv, tv);                \
        S.x = fmaf(f.x, S.x, buf[u].x); S.y = fmaf(f.y, S.y, buf[u].y);    \
        S.z = fmaf(f.z, S.z, buf[u].z); S.w = fmaf(f.w, S.w, buf[u].w);    \
        __builtin_nontemporal_store(*(const nf4*)&buf[u],                  \
            (nf4*)(st_base + (ptrdiff_t)((b) * 8 + u) * BH4));             \
    }

__global__ __launch_bounds__(256, 4) void k_mega(
    const float4* __restrict__ ht4, const float4* __restrict__ dv4,
    const float* __restrict__ sample, const float* __restrict__ hidden,
    const float* __restrict__ rb, const float* __restrict__ Wh,
    float* __restrict__ ws, float4* __restrict__ hc14)
{
    const int bid = blockIdx.x;
    const int tid = threadIdx.x;
    if (bid < 128) {
        __shared__ float As[BK][BM + 4];
        __shared__ float Wsh[BK][BN + 4];
        const int s = bid >> 5, t2 = bid & 31;
        const int bn = (t2 >> 2) << 6, bm = (t2 & 3) << 6, ks = s << 8;
        if (ks < 512)
            gemm64<false>(As, Wsh, sample + ks, nullptr, Wh, 1024, ks, bm, bn, 16,
                          ws + (size_t)s * BH);
        else
            gemm64<true>(As, Wsh, hidden + (ks - 512), rb + (ks - 512), Wh, 1024, ks,
                         bm, bn, 16, ws + (size_t)s * BH);
        return;
    }

    // factor table: f(m) = (m-d)/(m+1) = tinv - d*inv at idx m-1, m = 1..256
    __shared__ float s_inv[KF], s_tinv[KF];
    {
        const float fi = 1.0f / (float)(tid + 2);
        s_inv[tid] = fi; s_tinv[tid] = (float)(tid + 1) * fi;
    }
    __syncthreads();

    const int fb  = bid - 128;                   // 0..1023
    const int seg = fb >> 7;                     // 0..7
    const int q   = ((fb & 127) << 8) | tid;     // float4-column 0..32767
    const float4 d = dv4[q];
    const int j0  = 224 - (seg << 5);            // first ht slice (ascending)
    const int i0  = (seg << 5) + 31;             // LDS idx at u=0 (descending)

    const float4* ld_base = ht4 + (size_t)j0 * BH4 + q;
    float4*       st_base = hc14 + ((ptrdiff_t)j0 - 1) * BH4 + q;

    float4 S = make_float4(0.f, 0.f, 0.f, 0.f);

    float4 va[8], vb[8];
    FLOADB(va, 0);
    FLOADB(vb, 1);
    FCSTORE(va, 0);
    FLOADB(va, 2);
    FCSTORE(vb, 1);
    FLOADB(vb, 3);
    FCSTORE(va, 2);
    FCSTORE(vb, 3);

    const int slice = (seg < 4) ? (4 + seg) : (6 + seg);   // 4..7, 10..13
    ((float4*)ws)[(size_t)slice * BH4 + q] = S;
}

// finalize: recombine 8 ascending-Horner segment sums with prefix products
// F_s = prod f(32s+1..32s+32) (224-factor chain), h-parts reduce,
// hn = tanh(bh+sum h)*(1-z) + d*acc_inner  (filter_sum = f(0)*acc = -d*acc).
__global__ __launch_bounds__(256) void k_finalize(
    const float4* __restrict__ dv4, const float4* __restrict__ ws4,
    const float4* __restrict__ bh, const float4* __restrict__ zb4,
    float4* hc1_4, float4* __restrict__ hn_out)
{
    __shared__ float s_inv[224], s_tinv[224];
    const int tid = threadIdx.x;
    if (tid < 224) { const float fi = 1.0f / (float)(tid + 2);
                     s_inv[tid] = fi; s_tinv[tid] = (float)(tid + 1) * fi; }
    __syncthreads();

    const int g = blockIdx.x * 256 + tid;
    const int n = g & (H4 - 1);
    const float4 d = dv4[g];

    float4 acc = ws4[(size_t)4 * BH4 + g];           // G_0 (n in [0,31])
    float4 c = make_float4(1.f, 1.f, 1.f, 1.f);
    #pragma unroll
    for (int sgm = 1; sgm < 8; ++sgm) {
        #pragma unroll
        for (int i = (sgm - 1) * 32; i < sgm * 32; ++i)
            cupd(c, d, s_inv[i], s_tinv[i]);         // c *= f(i+1)
        const int sl = (sgm < 4) ? (4 + sgm) : (6 + sgm);
        const float4 ai = ws4[(size_t)sl * BH4 + g];
        afma(acc, ai, c);
    }

    float4 hs = bh[n];
    #pragma unroll
    for (int s = 0; s < 4; ++s) { const float4 p = ws4[(size_t)s * BH4 + g];
        hs.x += p.x; hs.y += p.y; hs.z += p.z; hs.w += p.w; }
    const float4 z = zb4[g];

    float4 hn;
    hn.x = fmaf(d.x, acc.x, tanh_fast(hs.x) * (1.0f - z.x));
    hn.y = fmaf(d.y, acc.y, tanh_fast(hs.y) * (1.0f - z.y));
    hn.z = fmaf(d.z, acc.z, tanh_fast(hs.z) * (1.0f - z.z));
    hn.w = fmaf(d.w, acc.w, tanh_fast(hs.w) * (1.0f - z.w));
    hn_out[g] = hn;
    hc1_4[(size_t)255 * BH4 + g] = hn;
}

__global__ __launch_bounds__(256) void k_gemm_o(
    const float* __restrict__ hn, const float* __restrict__ Wo,
    float* __restrict__ parts, int chunk)
{
    __shared__ float As[BK][BM + 4];
    __shared__ float Ws[BK][BN + 4];
    const int s = blockIdx.z, ks = s * chunk;
    gemm64<false>(As, Ws, hn + ks, nullptr, Wo, 512, ks,
                  blockIdx.y * BM, blockIdx.x * BN, chunk / BK, parts + (size_t)s * BH);
}

// no __restrict__: fallback path calls with parts == out (same-thread RMW)
__global__ __launch_bounds__(256) void k_reduce_o(
    const float4* parts, const float4* __restrict__ bo, float4* out, int NS)
{
    const int g = blockIdx.x * 256 + threadIdx.x;
    float4 v = bo[g & (H4 - 1)];
    for (int s = 0; s < NS; ++s) { const float4 p = parts[(size_t)s * BH4 + g];
        v.x += p.x; v.y += p.y; v.z += p.z; v.w += p.w; }
    out[g] = v;
}

// ------------------------- fallback-only kernels ---------------------------
__global__ __launch_bounds__(256) void k_reduce_rz(
    const float4* __restrict__ parts, const float4* __restrict__ br,
    const float4* __restrict__ bz, float4* __restrict__ rb, float4* __restrict__ zb)
{
    const int g = blockIdx.x * 256 + threadIdx.x;
    const int n = g & (H4 - 1);
    float4 r = br[n], z = bz[n];
    #pragma unroll
    for (int s = 0; s < 4; ++s) { const float4 p = parts[(size_t)s * BH4 + g];
        r.x += p.x; r.y += p.y; r.z += p.z; r.w += p.w; }
    #pragma unroll
    for (int s = 4; s < 8; ++s) { const float4 p = parts[(size_t)s * BH4 + g];
        z.x += p.x; z.y += p.y; z.z += p.z; z.w += p.w; }
    rb[g] = sig4(r); zb[g] = sig4(z);
}

__global__ __launch_bounds__(256) void k_gemm_h(
    const float* __restrict__ sample, const float* __restrict__ hidden,
    const float* __restrict__ rb, const float* __restrict__ Wh,
    float* __restrict__ parts)
{
    __shared__ float As[BK][BM + 4];
    __shared__ float Ws[BK][BN + 4];
    const int s = blockIdx.z, ks = s << 8;
    if (ks < 512)
        gemm64<false>(As, Ws, sample + ks, nullptr, Wh, 1024, ks,
                      blockIdx.y * BM, blockIdx.x * BN, 16, parts + (size_t)s * BH);
    else
        gemm64<true>(As, Ws, hidden + (ks - 512), rb + (ks - 512), Wh, 1024, ks,
                     blockIdx.y * BM, blockIdx.x * BN, 16, parts + (size_t)s * BH);
}

__global__ __launch_bounds__(256) void k_filter_full(
    const float* __restrict__ ht, const float* dparts, const float* __restrict__ bd,
    const float* zbuf, const float* hparts, const float* __restrict__ bh,
    float* hc1, float* __restrict__ dv_out, float* __restrict__ hn_out)
{
    __shared__ float s_inv[KF], s_tinv[KF];
    const int tid = threadIdx.x;
    const float fi = 1.0f / (float)(tid + 1);
    s_inv[tid] = fi; s_tinv[tid] = (float)tid * fi;
    __syncthreads();

    const int g = blockIdx.x * 256 + tid;
    const int n = g & (H_ - 1);
    float sd = bd[n];
    #pragma unroll
    for (int s = 0; s < 6; ++s) sd += dparts[(size_t)s * BH + g];
    const float d = 0.5f * sigmoidf_(sd);
    dv_out[g] = d;
    float sh = bh[n];
    #pragma unroll
    for (int s = 0; s < 4; ++s) sh += hparts[(size_t)s * BH + g];
    const float z = zbuf[g];

    float c = 1.0f, acc = 0.0f;
    #pragma unroll 16
    for (int t = 0; t < KF; ++t) {
        const int k = KF - 1 - t;
        const float v = ht[(size_t)k * BH + g];
        c *= fmaf(-d, s_inv[t], s_tinv[t]);
        acc = fmaf(v, c, acc);
        if (k >= 1) hc1[(size_t)(k - 1) * BH + g] = v;
    }
    const float hn = tanh_fast(sh) * (1.0f - z) - acc;
    hc1[(size_t)(KF - 1) * BH + g] = hn;
    hn_out[g] = hn;
}

extern "C" void kernel_launch(void* const* d_in, const int* in_sizes, int n_in,
                              void* d_out, int out_size, void* d_ws, size_t ws_size,
                              hipStream_t stream)
{
    const float* sample = (const float*)d_in[0];
    const float* hidden = (const float*)d_in[1];
    const float* ht     = (const float*)d_in[2];
    const float* d0     = (const float*)d_in[3];
    const float* Wd = (const float*)d_in[4];
    const float* bd = (const float*)d_in[5];
    const float* Wr = (const float*)d_in[6];
    const float* br = (const float*)d_in[7];
    const float* Wz = (const float*)d_in[8];
    const float* bz = (const float*)d_in[9];
    const float* Wh = (const float*)d_in[10];
    const float* bh = (const float*)d_in[11];
    const float* Wo = (const float*)d_in[12];
    const float* bo = (const float*)d_in[13];

    float* out     = (float*)d_out;
    float* out_o   = out;
    float* out_hn  = out + BH;
    float* out_hc1 = out + 2 * BH;
    float* out_dv  = out + 2 * BH + (size_t)KF * BH;

    const size_t slice = BH;
    const size_t need = 14ull * slice * sizeof(float);

    if (ws_size >= need) {
        float* ws = (float*)d_ws;
        // ws slices: [0..3] r-parts -> h-parts -> o-parts
        //            [4..7] z-parts -> filter accs 0..3
        //            [8] rb, [9] zb, [10..13] filter accs 4..7
        // d-parts -> hc1 slices 0..5 (dead after k_dv, overwritten by filter).
        float* rb = ws + 8 * slice;
        float* zb = ws + 9 * slice;

        k_gemm_drz<<<dim3(8, 4, 14), 256, 0, stream>>>(sample, hidden, d0,
                                                       Wd, Wr, Wz, out_hc1, ws);
        k_dv<<<dim3(128), 256, 0, stream>>>(
            (const float4*)out_hc1, (const float4*)bd,
            (const float4*)ws, (const float4*)br, (const float4*)bz,
            (float4*)out_dv, (float4*)rb, (float4*)zb);
        k_mega<<<dim3(1152), 256, 0, stream>>>(
            (const float4*)ht, (const float4*)out_dv, sample, hidden, rb, Wh,
            ws, (float4*)out_hc1);
        k_finalize<<<dim3(128), 256, 0, stream>>>(
            (const float4*)out_dv, (const float4*)ws,
            (const float4*)bh, (const float4*)zb,
            (float4*)out_hc1, (float4*)out_hn);
        k_gemm_o<<<dim3(8, 4, 4), 256, 0, stream>>>(out_hn, Wo, ws, 128);
        k_reduce_o<<<dim3(128), 256, 0, stream>>>((const float4*)ws,
                                                  (const float4*)bo,
                                                  (float4*)out_o, 4);
    } else {
        // serial fallback, all scratch = dead hc1 slices
        float* sl = out_hc1;
        k_gemm_drz<<<dim3(8, 4, 14), 256, 0, stream>>>(sample, hidden, d0,
                                                       Wd, Wr, Wz, sl, sl + 6 * slice);
        k_reduce_rz<<<dim3(128), 256, 0, stream>>>((const float4*)(sl + 6 * slice),
                                                   (const float4*)br, (const float4*)bz,
                                                   (float4*)(sl + 14 * slice),
                                                   (float4*)(sl + 15 * slice));
        k_gemm_h<<<dim3(8, 4, 4), 256, 0, stream>>>(sample, hidden, sl + 14 * slice, Wh,
                                                    sl + 16 * slice);
        k_filter_full<<<dim3(512), 256, 0, stream>>>(ht, sl, bd, sl + 15 * slice,
                                                     sl + 16 * slice, bh,
                                                     out_hc1, out_dv, out_hn);
        k_gemm_o<<<dim3(8, 4, 1), 256, 0, stream>>>(out_hn, Wo, out_o, 512);
        k_reduce_o<<<dim3(128), 256, 0, stream>>>((const float4*)out_o, (const float4*)bo,
                                                  (float4*)out_o, 1);
    }
}